// Round 17
// baseline (215.885 us; speedup 1.0000x reference)
//
#include <hip/hip_runtime.h>
#include <stdint.h>

typedef __bf16 bf16x8 __attribute__((ext_vector_type(8)));
typedef short short8 __attribute__((ext_vector_type(8)));
typedef float f32x4 __attribute__((ext_vector_type(4)));
typedef float f32x8v __attribute__((ext_vector_type(8)));
typedef unsigned short u16x8 __attribute__((ext_vector_type(8)));

#define DEV static __device__ __forceinline__

DEV float b2f(unsigned short u) {
    union { float f; unsigned v; } x; x.v = ((unsigned)u) << 16; return x.f;
}
DEV unsigned short f2b(float f) {
    union { float f; unsigned v; } x; x.f = f;
    unsigned r = x.v + 0x7fffu + ((x.v >> 16) & 1u);
    return (unsigned short)(r >> 16);
}
DEV f32x4 zero4() { f32x4 z; z[0]=0.f; z[1]=0.f; z[2]=0.f; z[3]=0.f; return z; }

#define MFMA16(a, b, c) __builtin_amdgcn_mfma_f32_16x16x32_bf16(a, b, c, 0, 0, 0)

// async global->LDS, 16B per lane; dest = wave-uniform base + lane*16
DEV void gload16(const unsigned short* g, unsigned short* l) {
    __builtin_amdgcn_global_load_lds(
        (const __attribute__((address_space(1))) void*)g,
        (__attribute__((address_space(3))) void*)l,
        16, 0, 0);
}

// ---------------------------------------------------------------------------
// Fused prep: cvt(x), cvt(proj_w), weff, rpb in ONE grid-strided kernel.
// Conversions are 8-wide (32B loads / 16B stores per lane, G13).
// ---------------------------------------------------------------------------
__global__ __launch_bounds__(256)
void prep_kernel(const float* __restrict__ x, unsigned short* __restrict__ xb,
                 const float* __restrict__ pw, unsigned short* __restrict__ pwb,
                 const float* __restrict__ qkvw,
                 const float* __restrict__ qa, const float* __restrict__ qbb,
                 const float* __restrict__ ka, const float* __restrict__ kb,
                 const float* __restrict__ va, const float* __restrict__ vbb,
                 unsigned short* __restrict__ W,
                 const float* __restrict__ rtab, const int* __restrict__ ridx,
                 float* __restrict__ rpb)
{
    const int S0 = 9682944 / 8;            // cvt x (8-vec tasks)
    const int S1 = 589824 / 8;             // cvt proj_w
    const int S2 = 2304 * 768;             // weff elements
    const int S3 = 12 * 197 * 224;         // rpb elements
    const int total = S0 + S1 + S2 + S3;
    for (int i = blockIdx.x * 256 + threadIdx.x; i < total; i += gridDim.x * 256) {
        if (i < S0) {
            f32x8v v = *(const f32x8v*)(x + (size_t)i * 8);
            u16x8 o;
            #pragma unroll
            for (int j = 0; j < 8; ++j) o[j] = f2b(v[j]);
            *(u16x8*)(xb + (size_t)i * 8) = o;
        } else if (i < S0 + S1) {
            const int k = i - S0;
            f32x8v v = *(const f32x8v*)(pw + (size_t)k * 8);
            u16x8 o;
            #pragma unroll
            for (int j = 0; j < 8; ++j) o[j] = f2b(v[j]);
            *(u16x8*)(pwb + (size_t)k * 8) = o;
        } else if (i < S0 + S1 + S2) {
            const int idx = i - S0 - S1;
            const int o = idx / 768;
            const int c = idx - o * 768;
            const int sec = o / 768;
            const int ol = o - sec * 768;
            const float* a_ = (sec == 0) ? qa : (sec == 1 ? ka : va);
            const float* b_ = (sec == 0) ? qbb : (sec == 1 ? kb : vbb);
            float acc = qkvw[idx];
            #pragma unroll
            for (int r = 0; r < 24; ++r)
                acc += b_[ol * 24 + r] * a_[r * 768 + c];
            W[idx] = f2b(acc);
        } else {
            const int idx = i - S0 - S1 - S2;
            const int h = idx / (197 * 224);
            const int rem = idx - h * 197 * 224;
            const int qq = rem / 224;
            const int kk = rem - qq * 224;
            float v = 0.f;
            if (kk < 197) v = rtab[ridx[qq * 197 + kk] * 12 + h];
            rpb[idx] = v;
        }
    }
}

// ---------------------------------------------------------------------------
// GEMM  C[M,N] = A[M,K=768] * Bw[N,K]^T  (bf16), f32 acc. 256x128 tile, BK=32.
// r16's 3-buffer counted-vmcnt skeleton at 16 WAVES per block (1024 thr):
// 2 blocks/CU (LDS 72KB; wave-cap 32/16=2) -> 8 waves/SIMD = hardware max.
// Per-wave: 64x32 output (4M x 4N wave grid), 8 MFMA + 6 ds_read/step.
// Staging: A (16KB) = 1 gload16/thread; B (8KB) = 1 gload16 for tid<512.
// Asymmetric per-wave vmcnt handled via readfirstlane-scalar branch:
// waves 0-7 (A+B, 2 loads/stage): vmcnt(2); waves 8-15 (A only): vmcnt(1).
// Byte-involution swizzle F(b)=b^(((b>>7)&7)<<4) (0 measured conflicts;
// pattern repeats per 1KB so the 256-row A tile inherits it). XCD remap m204.
// ---------------------------------------------------------------------------
template<int EPI>
__global__ __launch_bounds__(1024, 2)
void gemm_bt(const unsigned short* __restrict__ A, const unsigned short* __restrict__ Bw,
             int M, int Nout, int ntn,
             const float* __restrict__ qb, const float* __restrict__ vb,
             const float* __restrict__ rcos, const float* __restrict__ rsin,
             unsigned short* __restrict__ oq, unsigned short* __restrict__ ok,
             unsigned short* __restrict__ ov,
             const float* __restrict__ pb, float* __restrict__ o2)
{
    constexpr int K = 768, TK = 24;     // TK % 3 == 0 required
    __shared__ __align__(16) unsigned short lA[3][256 * 32];
    __shared__ __align__(16) unsigned short lB[3][128 * 32];
    const int tid = threadIdx.x;
    const int lane = tid & 63, wave = tid >> 6;       // wave 0..15
    const int wlead = __builtin_amdgcn_readfirstlane(wave);

    // bijective XCD-aware remap (m204)
    const int nwg = gridDim.x;
    const int qq_ = nwg >> 3, rr_ = nwg & 7;
    const int xcd = blockIdx.x & 7, orig8 = blockIdx.x >> 3;
    const int wgid = (xcd < rr_ ? xcd * (qq_ + 1) : rr_ * (qq_ + 1) + (xcd - rr_) * qq_) + orig8;
    const int mt = wgid / ntn, nt = wgid - mt * ntn;
    const int m0 = mt * 256, n0 = nt * 128;
    const int wm = (wave >> 2) * 64;      // 4 row-groups of 64
    const int wn = (wave & 3) * 32;       // 4 col-groups of 32

    // staging geometry: thread writes phys byte P = tid*16; source = logical
    // L = F(P): row L>>6, 16B-unit (L>>4)&3. (A: 16KB; B: 8KB, tid<512)
    const int P = tid * 16;
    const int L = P ^ (((P >> 7) & 7) << 4);
    const int srow = L >> 6;              // A: 0..255; B (tid<512): 0..127
    const int sunit = (L >> 4) & 3;

    // read-side physical element offsets (loop-invariant)
    const int laneA = lane & 15, laneQ = lane >> 4;
    int aoff[4], boff[2];
    #pragma unroll
    for (int i = 0; i < 4; ++i) {
        int lb = (wm + i * 16 + laneA) * 64 + laneQ * 16;        // logical byte
        aoff[i] = (lb ^ (((lb >> 7) & 7) << 4)) >> 1;            // phys elem
    }
    #pragma unroll
    for (int i = 0; i < 2; ++i) {
        int lb = (wn + i * 16 + laneA) * 64 + laneQ * 16;
        boff[i] = (lb ^ (((lb >> 7) & 7) << 4)) >> 1;
    }

    f32x4 acc[4][2];
    #pragma unroll
    for (int i = 0; i < 4; ++i)
        #pragma unroll
        for (int j = 0; j < 2; ++j) acc[i][j] = zero4();

    auto stage = [&](int kt, int bsel) {
        const int k0 = kt << 5;
        int gr = m0 + srow; if (gr > M - 1) gr = M - 1;
        gload16(A + (size_t)gr * K + k0 + sunit * 8,
                (unsigned short*)lA[bsel] + tid * 8);
        if (wlead < 8) {                  // scalar branch: waves 0..7 only
            const int br = n0 + srow;     // srow 0..127 here; Nout%128==0
            gload16(Bw + (size_t)br * K + k0 + sunit * 8,
                    (unsigned short*)lB[bsel] + tid * 8);
        }
    };

    // prologue: tiles 0,1 in flight; wait tile 0 (tile 1's loads may lag)
    stage(0, 0);
    stage(1, 1);
    if (wlead < 8) asm volatile("s_waitcnt vmcnt(2)" ::: "memory");
    else           asm volatile("s_waitcnt vmcnt(1)" ::: "memory");
    __builtin_amdgcn_s_barrier();

    #pragma unroll
    for (int t = 0; t < TK; ++t) {
        if (t + 2 < TK) stage(t + 2, (t + 2) % 3);       // const-folded
        const unsigned short* aT = (const unsigned short*)lA[t % 3];
        const unsigned short* bT = (const unsigned short*)lB[t % 3];
        bf16x8 af[4], bfr[2];
        #pragma unroll
        for (int i = 0; i < 4; ++i) af[i] = *(const bf16x8*)(aT + aoff[i]);
        #pragma unroll
        for (int i = 0; i < 2; ++i) bfr[i] = *(const bf16x8*)(bT + boff[i]);
        #pragma unroll
        for (int mi = 0; mi < 4; ++mi)
            #pragma unroll
            for (int ni = 0; ni < 2; ++ni)
                acc[mi][ni] = MFMA16(af[mi], bfr[ni], acc[mi][ni]);
        if (t + 1 < TK) {
            if (t + 2 < TK) {
                if (wlead < 8) asm volatile("s_waitcnt vmcnt(2)" ::: "memory");
                else           asm volatile("s_waitcnt vmcnt(1)" ::: "memory");
            } else {
                asm volatile("s_waitcnt vmcnt(0)" ::: "memory");
            }
            __builtin_amdgcn_s_barrier();
        }
    }

    #pragma unroll
    for (int mi = 0; mi < 4; ++mi) {
        #pragma unroll
        for (int j = 0; j < 4; ++j) {
            const int m = m0 + wm + mi * 16 + laneQ * 4 + j;
            const bool mv = (m < M);
            int b_ = 0, n = 0;
            if constexpr (EPI == 1) { b_ = m / 197; n = m - b_ * 197; }
            #pragma unroll
            for (int ni = 0; ni < 2; ++ni) {
                const int o = n0 + wn + ni * 16 + laneA;
                float val = acc[mi][ni][j];
                if constexpr (EPI == 1) {
                    const int sec = o / 768;
                    const int oc = o - sec * 768;
                    const int d = oc & 63;
                    if (sec == 0) val += qb[oc];
                    else if (sec == 2) val += vb[oc];
                    if (sec < 2 && n > 0) {
                        const float part = __shfl_xor(val, 1, 64);
                        const float co = rcos[(n - 1) * 64 + d];
                        const float si = rsin[(n - 1) * 64 + d];
                        val = val * co + ((o & 1) ? part : -part) * si;
                    }
                    if (sec == 0) val *= 0.125f;
                    if (mv) {
                        const int h = oc >> 6;
                        unsigned short* dst = (sec == 0) ? oq : (sec == 1 ? ok : ov);
                        dst[((size_t)(b_ * 12 + h) * 197 + n) * 64 + d] = f2b(val);
                    }
                } else {
                    val += pb[o];
                    if (mv) o2[(size_t)m * Nout + o] = val;
                }
            }
        }
    }
}

// ---------------------------------------------------------------------------
// Fused attention per (b,h,64-row q-chunk): S=q@k^T (+rpb), softmax in regs,
// P@V via LDS (Vt transposed in LDS). Stride 208 -> LDS 53.25 KB ->
// 3 blocks/CU. Last PV k-chunk via 16B zero-page for laneK>=16.
// inv_s LDS removed (sm[j] already in the owning lanes).
// ---------------------------------------------------------------------------
__global__ __launch_bounds__(256, 3)
void attn_kernel(const unsigned short* __restrict__ qs, const unsigned short* __restrict__ ksrc,
                 const unsigned short* __restrict__ vsrc, const float* __restrict__ rpb,
                 unsigned short* __restrict__ aout)
{
    __shared__ __align__(16) unsigned short Pl[64 * 208];
    __shared__ __align__(16) unsigned short Vt[64 * 208];
    __shared__ __align__(16) unsigned short zpage[8];   // 16B of zeros
    const int chunk = blockIdx.x;   // 0..3
    const int h = blockIdx.y;       // 0..11
    const int b = blockIdx.z;       // 0..63
    const int tid = threadIdx.x, lane = tid & 63, wave = tid >> 6;
    const size_t base = ((size_t)(b * 12 + h)) * 197 * 64;
    const unsigned short* q = qs + base;
    const unsigned short* kp = ksrc + base;
    const unsigned short* vp = vsrc + base;

    if (tid < 8) zpage[tid] = 0;

    // stage V^T into LDS (cols 197..207 zeroed; avoids NaN*0)
    if (tid < 208) {
        const int kc = tid;
        if (kc < 197) {
            #pragma unroll
            for (int d0 = 0; d0 < 8; ++d0) {
                short8 vv = *(const short8*)(vp + kc * 64 + d0 * 8);
                #pragma unroll
                for (int i = 0; i < 8; ++i)
                    Vt[(d0 * 8 + i) * 208 + kc] = (unsigned short)vv[i];
            }
        } else {
            #pragma unroll
            for (int dd = 0; dd < 64; ++dd) Vt[dd * 208 + kc] = 0;
        }
    }

    const int laneA = lane & 15;
    const int laneK = (lane >> 4) * 8;
    const int q0 = chunk * 64 + wave * 16;

    int qr = q0 + laneA; if (qr > 196) qr = 196;
    const bf16x8 qf0 = *(const bf16x8*)(q + qr * 64 + laneK);
    const bf16x8 qf1 = *(const bf16x8*)(q + qr * 64 + 32 + laneK);

    f32x4 s[13];
    #pragma unroll
    for (int kt = 0; kt < 13; ++kt) {
        int kr = kt * 16 + laneA; if (kr > 196) kr = 196;
        const bf16x8 kf0 = *(const bf16x8*)(kp + kr * 64 + laneK);
        const bf16x8 kf1 = *(const bf16x8*)(kp + kr * 64 + 32 + laneK);
        f32x4 c = zero4();
        c = MFMA16(qf0, kf0, c);
        c = MFMA16(qf1, kf1, c);
        s[kt] = c;
    }

    const int rowb = (lane >> 4) * 4;
    float mx[4] = {-1e30f, -1e30f, -1e30f, -1e30f};
    #pragma unroll
    for (int kt = 0; kt < 13; ++kt) {
        const int kc = kt * 16 + laneA;
        #pragma unroll
        for (int j = 0; j < 4; ++j) {
            int qg = q0 + rowb + j; if (qg > 196) qg = 196;
            float v = s[kt][j] + rpb[((size_t)h * 197 + qg) * 224 + kc];
            if (kc > 196) v = -1e30f;
            s[kt][j] = v;
            mx[j] = fmaxf(mx[j], v);
        }
    }
    #pragma unroll
    for (int off = 1; off < 16; off <<= 1)
        #pragma unroll
        for (int j = 0; j < 4; ++j) mx[j] = fmaxf(mx[j], __shfl_xor(mx[j], off, 64));
    float sm[4] = {0.f, 0.f, 0.f, 0.f};
    #pragma unroll
    for (int kt = 0; kt < 13; ++kt)
        #pragma unroll
        for (int j = 0; j < 4; ++j) {
            const float e = __expf(s[kt][j] - mx[j]);
            s[kt][j] = e;
            sm[j] += e;
        }
    #pragma unroll
    for (int off = 1; off < 16; off <<= 1)
        #pragma unroll
        for (int j = 0; j < 4; ++j) sm[j] += __shfl_xor(sm[j], off, 64);
    float rs[4];
    #pragma unroll
    for (int j = 0; j < 4; ++j) rs[j] = 1.0f / sm[j];

    #pragma unroll
    for (int kt = 0; kt < 13; ++kt) {
        const int kc = kt * 16 + laneA;
        #pragma unroll
        for (int j = 0; j < 4; ++j) {
            const int lr = wave * 16 + rowb + j;
            Pl[lr * 208 + kc] = (kc <= 196) ? f2b(s[kt][j]) : (unsigned short)0;
        }
    }

    __syncthreads();

    f32x4 oacc[4];
    #pragma unroll
    for (int i = 0; i < 4; ++i) oacc[i] = zero4();
    const unsigned short* plrow = Pl + (wave * 16 + laneA) * 208;
    #pragma unroll
    for (int ks2 = 0; ks2 < 6; ++ks2) {
        const bf16x8 pf = *(const bf16x8*)(plrow + ks2 * 32 + laneK);
        #pragma unroll
        for (int ni = 0; ni < 4; ++ni) {
            const bf16x8 vf = *(const bf16x8*)(Vt + (ni * 16 + laneA) * 208 + ks2 * 32 + laneK);
            oacc[ni] = MFMA16(pf, vf, oacc[ni]);
        }
    }
    {   // last chunk: k 192..207 real (207.. zero); laneK>=16 reads zero-page
        const bool hi = (laneK >= 16);
        const bf16x8 pf = *(const bf16x8*)(hi ? zpage : plrow + 192 + laneK);
        #pragma unroll
        for (int ni = 0; ni < 4; ++ni) {
            const bf16x8 vf = *(const bf16x8*)(hi ? zpage
                                : Vt + (ni * 16 + laneA) * 208 + 192 + laneK);
            oacc[ni] = MFMA16(pf, vf, oacc[ni]);
        }
    }
    #pragma unroll
    for (int ni = 0; ni < 4; ++ni)
        #pragma unroll
        for (int j = 0; j < 4; ++j) {
            const int qg = chunk * 64 + wave * 16 + rowb + j;
            if (qg < 197) {
                const int d = ni * 16 + laneA;
                const float val = oacc[ni][j] * rs[j];
                aout[((size_t)b * 197 + qg) * 768 + h * 64 + d] = f2b(val);
            }
        }
}

// ---------------------------------------------------------------------------
extern "C" void kernel_launch(void* const* d_in, const int* in_sizes, int n_in,
                              void* d_out, int out_size, void* d_ws, size_t ws_size,
                              hipStream_t stream)
{
    const float* x    = (const float*)d_in[0];
    const float* qkvw = (const float*)d_in[1];
    const float* qb   = (const float*)d_in[2];
    const float* vb   = (const float*)d_in[3];
    const float* lqa  = (const float*)d_in[4];
    const float* lqb  = (const float*)d_in[5];
    const float* lka  = (const float*)d_in[6];
    const float* lkb  = (const float*)d_in[7];
    const float* lva  = (const float*)d_in[8];
    const float* lvb  = (const float*)d_in[9];
    const float* rtab = (const float*)d_in[10];
    const float* rcos = (const float*)d_in[11];
    const float* rsin = (const float*)d_in[12];
    const float* pw   = (const float*)d_in[13];
    const float* pb   = (const float*)d_in[14];
    const int* ridx   = (const int*)d_in[15];

    const int M = 64 * 197;                        // 12608
    const size_t XSZ = (size_t)M * 768;            // 9,682,944
    const size_t QSZ = (size_t)64 * 12 * 197 * 64; // 9,682,944

    char* ws = (char*)d_ws;
    unsigned short* xb   = (unsigned short*)ws;                    // XSZ
    unsigned short* pwb  = xb + XSZ;                               // 768*768
    unsigned short* Weff = pwb + (size_t)768 * 768;                // 2304*768
    unsigned short* qsb  = Weff + (size_t)2304 * 768;
    unsigned short* ksb  = qsb + QSZ;
    unsigned short* vsb  = ksb + QSZ;
    float* rpb           = (float*)(vsb + QSZ);                    // 12*197*224 f32
    unsigned short* aout = (unsigned short*)(rpb + (size_t)12 * 197 * 224); // XSZ

    prep_kernel<<<2048, 256, 0, stream>>>(x, xb, pw, pwb, qkvw,
                                          lqa, lqb, lka, lkb, lva, lvb, Weff,
                                          rtab, ridx, rpb);
    const int MT = (M + 255) / 256;                // 50 m-tiles of 256
    gemm_bt<1><<<MT * 18, 1024, 0, stream>>>(xb, Weff, M, 2304, 18,
                                             qb, vb, rcos, rsin, qsb, ksb, vsb,
                                             nullptr, nullptr);
    attn_kernel<<<dim3(4, 12, 64), 256, 0, stream>>>(qsb, ksb, vsb, rpb, aout);
    gemm_bt<2><<<MT * 6, 1024, 0, stream>>>(aout, pwb, M, 768, 6,
                                            nullptr, nullptr, nullptr, nullptr,
                                            nullptr, nullptr, nullptr,
                                            pb, (float*)d_out);
}

// Round 18
// 192.908 us; speedup vs baseline: 1.1191x; 1.1191x over previous
//
#include <hip/hip_runtime.h>
#include <stdint.h>

typedef __bf16 bf16x8 __attribute__((ext_vector_type(8)));
typedef short short8 __attribute__((ext_vector_type(8)));
typedef float f32x4 __attribute__((ext_vector_type(4)));
typedef float f32x8v __attribute__((ext_vector_type(8)));
typedef unsigned short u16x8 __attribute__((ext_vector_type(8)));

#define DEV static __device__ __forceinline__

DEV float b2f(unsigned short u) {
    union { float f; unsigned v; } x; x.v = ((unsigned)u) << 16; return x.f;
}
DEV unsigned short f2b(float f) {
    union { float f; unsigned v; } x; x.f = f;
    unsigned r = x.v + 0x7fffu + ((x.v >> 16) & 1u);
    return (unsigned short)(r >> 16);
}
DEV f32x4 zero4() { f32x4 z; z[0]=0.f; z[1]=0.f; z[2]=0.f; z[3]=0.f; return z; }

#define MFMA16(a, b, c) __builtin_amdgcn_mfma_f32_16x16x32_bf16(a, b, c, 0, 0, 0)

// async global->LDS, 16B per lane; dest = wave-uniform base + lane*16
DEV void gload16(const unsigned short* g, unsigned short* l) {
    __builtin_amdgcn_global_load_lds(
        (const __attribute__((address_space(1))) void*)g,
        (__attribute__((address_space(3))) void*)l,
        16, 0, 0);
}

// ---------------------------------------------------------------------------
// Fused prep: cvt(x), cvt(proj_w), weff, rpb in ONE grid-strided kernel.
// Conversions are 8-wide (32B loads / 16B stores per lane, G13).
// ---------------------------------------------------------------------------
__global__ __launch_bounds__(256)
void prep_kernel(const float* __restrict__ x, unsigned short* __restrict__ xb,
                 const float* __restrict__ pw, unsigned short* __restrict__ pwb,
                 const float* __restrict__ qkvw,
                 const float* __restrict__ qa, const float* __restrict__ qbb,
                 const float* __restrict__ ka, const float* __restrict__ kb,
                 const float* __restrict__ va, const float* __restrict__ vbb,
                 unsigned short* __restrict__ W,
                 const float* __restrict__ rtab, const int* __restrict__ ridx,
                 float* __restrict__ rpb)
{
    const int S0 = 9682944 / 8;            // cvt x (8-vec tasks)
    const int S1 = 589824 / 8;             // cvt proj_w
    const int S2 = 2304 * 768;             // weff elements
    const int S3 = 12 * 197 * 224;         // rpb elements
    const int total = S0 + S1 + S2 + S3;
    for (int i = blockIdx.x * 256 + threadIdx.x; i < total; i += gridDim.x * 256) {
        if (i < S0) {
            f32x8v v = *(const f32x8v*)(x + (size_t)i * 8);
            u16x8 o;
            #pragma unroll
            for (int j = 0; j < 8; ++j) o[j] = f2b(v[j]);
            *(u16x8*)(xb + (size_t)i * 8) = o;
        } else if (i < S0 + S1) {
            const int k = i - S0;
            f32x8v v = *(const f32x8v*)(pw + (size_t)k * 8);
            u16x8 o;
            #pragma unroll
            for (int j = 0; j < 8; ++j) o[j] = f2b(v[j]);
            *(u16x8*)(pwb + (size_t)k * 8) = o;
        } else if (i < S0 + S1 + S2) {
            const int idx = i - S0 - S1;
            const int o = idx / 768;
            const int c = idx - o * 768;
            const int sec = o / 768;
            const int ol = o - sec * 768;
            const float* a_ = (sec == 0) ? qa : (sec == 1 ? ka : va);
            const float* b_ = (sec == 0) ? qbb : (sec == 1 ? kb : vbb);
            float acc = qkvw[idx];
            #pragma unroll
            for (int r = 0; r < 24; ++r)
                acc += b_[ol * 24 + r] * a_[r * 768 + c];
            W[idx] = f2b(acc);
        } else {
            const int idx = i - S0 - S1 - S2;
            const int h = idx / (197 * 224);
            const int rem = idx - h * 197 * 224;
            const int qq = rem / 224;
            const int kk = rem - qq * 224;
            float v = 0.f;
            if (kk < 197) v = rtab[ridx[qq * 197 + kk] * 12 + h];
            rpb[idx] = v;
        }
    }
}

// ---------------------------------------------------------------------------
// GEMM  C[M,N] = A[M,K=768] * Bw[N,K]^T  (bf16), f32 acc. 128x128 tile, BK=32.
// Session-optimal configuration (r16): 3-buffer counted-vmcnt pipeline with
// 8 WAVES per block (512 thr) at 48KB LDS: 3 blocks/CU -> 6 waves/SIMD.
// Per-wave: 64x32 output (2M x 4N wave grid), 8 MFMA + 6 ds_read_b128/step,
// staging = exactly 1 gload16 per thread per matrix per tile.
// Per-wave vmcnt: 2 loads/stage -> steady vmcnt(2), tail vmcnt(0).
// Byte-involution swizzle F(b)=b^(((b>>7)&7)<<4) (0 measured conflicts),
// bijective XCD remap (m204).
// Response surface mapped r3-r17: deeper (4-buf), wider (256^2), shallower
// (drain-0), LDS-free, hybrid, 8-phase, 16-wave blocks all measured worse.
// ---------------------------------------------------------------------------
template<int EPI>
__global__ __launch_bounds__(512, 6)
void gemm_bt(const unsigned short* __restrict__ A, const unsigned short* __restrict__ Bw,
             int M, int Nout, int ntn,
             const float* __restrict__ qb, const float* __restrict__ vb,
             const float* __restrict__ rcos, const float* __restrict__ rsin,
             unsigned short* __restrict__ oq, unsigned short* __restrict__ ok,
             unsigned short* __restrict__ ov,
             const float* __restrict__ pb, float* __restrict__ o2)
{
    constexpr int K = 768, TK = 24;     // TK % 3 == 0 required
    __shared__ __align__(16) unsigned short lA[3][128 * 32];
    __shared__ __align__(16) unsigned short lB[3][128 * 32];
    const int tid = threadIdx.x;
    const int lane = tid & 63, wave = tid >> 6;       // wave 0..7

    // bijective XCD-aware remap (m204)
    const int nwg = gridDim.x;
    const int qq_ = nwg >> 3, rr_ = nwg & 7;
    const int xcd = blockIdx.x & 7, orig8 = blockIdx.x >> 3;
    const int wgid = (xcd < rr_ ? xcd * (qq_ + 1) : rr_ * (qq_ + 1) + (xcd - rr_) * qq_) + orig8;
    const int mt = wgid / ntn, nt = wgid - mt * ntn;
    const int m0 = mt * 128, n0 = nt * 128;
    const int wm = (wave >> 2) * 64;      // 2 row-halves
    const int wn = (wave & 3) * 32;       // 4 col-quarters

    // staging geometry: thread writes phys byte P = tid*16 of the 8KB tile;
    // source = logical L = F(P): row L>>6, 16B-unit (L>>4)&3.
    const int P = tid * 16;
    const int L = P ^ (((P >> 7) & 7) << 4);
    const int srow = L >> 6;
    const int sunit = (L >> 4) & 3;

    // read-side physical element offsets (loop-invariant)
    const int laneA = lane & 15, laneQ = lane >> 4;
    int aoff[4], boff[2];
    #pragma unroll
    for (int i = 0; i < 4; ++i) {
        int lb = (wm + i * 16 + laneA) * 64 + laneQ * 16;        // logical byte
        aoff[i] = (lb ^ (((lb >> 7) & 7) << 4)) >> 1;            // phys elem
    }
    #pragma unroll
    for (int i = 0; i < 2; ++i) {
        int lb = (wn + i * 16 + laneA) * 64 + laneQ * 16;
        boff[i] = (lb ^ (((lb >> 7) & 7) << 4)) >> 1;
    }

    f32x4 acc[4][2];
    #pragma unroll
    for (int i = 0; i < 4; ++i)
        #pragma unroll
        for (int j = 0; j < 2; ++j) acc[i][j] = zero4();

    auto stage = [&](int kt, int bsel) {
        const int k0 = kt << 5;
        int gr = m0 + srow; if (gr > M - 1) gr = M - 1;
        gload16(A + (size_t)gr * K + k0 + sunit * 8,
                (unsigned short*)lA[bsel] + tid * 8);
        const int br = n0 + srow;                               // Nout%128==0
        gload16(Bw + (size_t)br * K + k0 + sunit * 8,
                (unsigned short*)lB[bsel] + tid * 8);
    };

    // prologue: tiles 0,1 in flight (2 loads each per wave); wait tile 0
    stage(0, 0);
    stage(1, 1);
    asm volatile("s_waitcnt vmcnt(2)" ::: "memory");
    __builtin_amdgcn_s_barrier();

    #pragma unroll
    for (int t = 0; t < TK; ++t) {
        if (t + 2 < TK) stage(t + 2, (t + 2) % 3);       // const-folded
        const unsigned short* aT = (const unsigned short*)lA[t % 3];
        const unsigned short* bT = (const unsigned short*)lB[t % 3];
        bf16x8 af[4], bfr[2];
        #pragma unroll
        for (int i = 0; i < 4; ++i) af[i] = *(const bf16x8*)(aT + aoff[i]);
        #pragma unroll
        for (int i = 0; i < 2; ++i) bfr[i] = *(const bf16x8*)(bT + boff[i]);
        #pragma unroll
        for (int mi = 0; mi < 4; ++mi)
            #pragma unroll
            for (int ni = 0; ni < 2; ++ni)
                acc[mi][ni] = MFMA16(af[mi], bfr[ni], acc[mi][ni]);
        if (t + 1 < TK) {
            if (t + 2 < TK) asm volatile("s_waitcnt vmcnt(2)" ::: "memory");
            else            asm volatile("s_waitcnt vmcnt(0)" ::: "memory");
            __builtin_amdgcn_s_barrier();
        }
    }

    #pragma unroll
    for (int mi = 0; mi < 4; ++mi) {
        #pragma unroll
        for (int j = 0; j < 4; ++j) {
            const int m = m0 + wm + mi * 16 + laneQ * 4 + j;
            const bool mv = (m < M);
            int b_ = 0, n = 0;
            if constexpr (EPI == 1) { b_ = m / 197; n = m - b_ * 197; }
            #pragma unroll
            for (int ni = 0; ni < 2; ++ni) {
                const int o = n0 + wn + ni * 16 + laneA;
                float val = acc[mi][ni][j];
                if constexpr (EPI == 1) {
                    const int sec = o / 768;
                    const int oc = o - sec * 768;
                    const int d = oc & 63;
                    if (sec == 0) val += qb[oc];
                    else if (sec == 2) val += vb[oc];
                    if (sec < 2 && n > 0) {
                        const float part = __shfl_xor(val, 1, 64);
                        const float co = rcos[(n - 1) * 64 + d];
                        const float si = rsin[(n - 1) * 64 + d];
                        val = val * co + ((o & 1) ? part : -part) * si;
                    }
                    if (sec == 0) val *= 0.125f;
                    if (mv) {
                        const int h = oc >> 6;
                        unsigned short* dst = (sec == 0) ? oq : (sec == 1 ? ok : ov);
                        dst[((size_t)(b_ * 12 + h) * 197 + n) * 64 + d] = f2b(val);
                    }
                } else {
                    val += pb[o];
                    if (mv) o2[(size_t)m * Nout + o] = val;
                }
            }
        }
    }
}

// ---------------------------------------------------------------------------
// Fused attention per (b,h,64-row q-chunk): S=q@k^T (+rpb), softmax in regs,
// P@V via LDS (Vt transposed in LDS). Stride 208 -> LDS 53.25 KB ->
// 3 blocks/CU. Last PV k-chunk via 16B zero-page for laneK>=16.
// inv_s LDS removed (sm[j] already in the owning lanes).
// ---------------------------------------------------------------------------
__global__ __launch_bounds__(256, 3)
void attn_kernel(const unsigned short* __restrict__ qs, const unsigned short* __restrict__ ksrc,
                 const unsigned short* __restrict__ vsrc, const float* __restrict__ rpb,
                 unsigned short* __restrict__ aout)
{
    __shared__ __align__(16) unsigned short Pl[64 * 208];
    __shared__ __align__(16) unsigned short Vt[64 * 208];
    __shared__ __align__(16) unsigned short zpage[8];   // 16B of zeros
    const int chunk = blockIdx.x;   // 0..3
    const int h = blockIdx.y;       // 0..11
    const int b = blockIdx.z;       // 0..63
    const int tid = threadIdx.x, lane = tid & 63, wave = tid >> 6;
    const size_t base = ((size_t)(b * 12 + h)) * 197 * 64;
    const unsigned short* q = qs + base;
    const unsigned short* kp = ksrc + base;
    const unsigned short* vp = vsrc + base;

    if (tid < 8) zpage[tid] = 0;

    // stage V^T into LDS (cols 197..207 zeroed; avoids NaN*0)
    if (tid < 208) {
        const int kc = tid;
        if (kc < 197) {
            #pragma unroll
            for (int d0 = 0; d0 < 8; ++d0) {
                short8 vv = *(const short8*)(vp + kc * 64 + d0 * 8);
                #pragma unroll
                for (int i = 0; i < 8; ++i)
                    Vt[(d0 * 8 + i) * 208 + kc] = (unsigned short)vv[i];
            }
        } else {
            #pragma unroll
            for (int dd = 0; dd < 64; ++dd) Vt[dd * 208 + kc] = 0;
        }
    }

    const int laneA = lane & 15;
    const int laneK = (lane >> 4) * 8;
    const int q0 = chunk * 64 + wave * 16;

    int qr = q0 + laneA; if (qr > 196) qr = 196;
    const bf16x8 qf0 = *(const bf16x8*)(q + qr * 64 + laneK);
    const bf16x8 qf1 = *(const bf16x8*)(q + qr * 64 + 32 + laneK);

    f32x4 s[13];
    #pragma unroll
    for (int kt = 0; kt < 13; ++kt) {
        int kr = kt * 16 + laneA; if (kr > 196) kr = 196;
        const bf16x8 kf0 = *(const bf16x8*)(kp + kr * 64 + laneK);
        const bf16x8 kf1 = *(const bf16x8*)(kp + kr * 64 + 32 + laneK);
        f32x4 c = zero4();
        c = MFMA16(qf0, kf0, c);
        c = MFMA16(qf1, kf1, c);
        s[kt] = c;
    }

    const int rowb = (lane >> 4) * 4;
    float mx[4] = {-1e30f, -1e30f, -1e30f, -1e30f};
    #pragma unroll
    for (int kt = 0; kt < 13; ++kt) {
        const int kc = kt * 16 + laneA;
        #pragma unroll
        for (int j = 0; j < 4; ++j) {
            int qg = q0 + rowb + j; if (qg > 196) qg = 196;
            float v = s[kt][j] + rpb[((size_t)h * 197 + qg) * 224 + kc];
            if (kc > 196) v = -1e30f;
            s[kt][j] = v;
            mx[j] = fmaxf(mx[j], v);
        }
    }
    #pragma unroll
    for (int off = 1; off < 16; off <<= 1)
        #pragma unroll
        for (int j = 0; j < 4; ++j) mx[j] = fmaxf(mx[j], __shfl_xor(mx[j], off, 64));
    float sm[4] = {0.f, 0.f, 0.f, 0.f};
    #pragma unroll
    for (int kt = 0; kt < 13; ++kt)
        #pragma unroll
        for (int j = 0; j < 4; ++j) {
            const float e = __expf(s[kt][j] - mx[j]);
            s[kt][j] = e;
            sm[j] += e;
        }
    #pragma unroll
    for (int off = 1; off < 16; off <<= 1)
        #pragma unroll
        for (int j = 0; j < 4; ++j) sm[j] += __shfl_xor(sm[j], off, 64);
    float rs[4];
    #pragma unroll
    for (int j = 0; j < 4; ++j) rs[j] = 1.0f / sm[j];

    #pragma unroll
    for (int kt = 0; kt < 13; ++kt) {
        const int kc = kt * 16 + laneA;
        #pragma unroll
        for (int j = 0; j < 4; ++j) {
            const int lr = wave * 16 + rowb + j;
            Pl[lr * 208 + kc] = (kc <= 196) ? f2b(s[kt][j]) : (unsigned short)0;
        }
    }

    __syncthreads();

    f32x4 oacc[4];
    #pragma unroll
    for (int i = 0; i < 4; ++i) oacc[i] = zero4();
    const unsigned short* plrow = Pl + (wave * 16 + laneA) * 208;
    #pragma unroll
    for (int ks2 = 0; ks2 < 6; ++ks2) {
        const bf16x8 pf = *(const bf16x8*)(plrow + ks2 * 32 + laneK);
        #pragma unroll
        for (int ni = 0; ni < 4; ++ni) {
            const bf16x8 vf = *(const bf16x8*)(Vt + (ni * 16 + laneA) * 208 + ks2 * 32 + laneK);
            oacc[ni] = MFMA16(pf, vf, oacc[ni]);
        }
    }
    {   // last chunk: k 192..207 real (207.. zero); laneK>=16 reads zero-page
        const bool hi = (laneK >= 16);
        const bf16x8 pf = *(const bf16x8*)(hi ? zpage : plrow + 192 + laneK);
        #pragma unroll
        for (int ni = 0; ni < 4; ++ni) {
            const bf16x8 vf = *(const bf16x8*)(hi ? zpage
                                : Vt + (ni * 16 + laneA) * 208 + 192 + laneK);
            oacc[ni] = MFMA16(pf, vf, oacc[ni]);
        }
    }
    #pragma unroll
    for (int ni = 0; ni < 4; ++ni)
        #pragma unroll
        for (int j = 0; j < 4; ++j) {
            const int qg = chunk * 64 + wave * 16 + rowb + j;
            if (qg < 197) {
                const int d = ni * 16 + laneA;
                const float val = oacc[ni][j] * rs[j];
                aout[((size_t)b * 197 + qg) * 768 + h * 64 + d] = f2b(val);
            }
        }
}

// ---------------------------------------------------------------------------
extern "C" void kernel_launch(void* const* d_in, const int* in_sizes, int n_in,
                              void* d_out, int out_size, void* d_ws, size_t ws_size,
                              hipStream_t stream)
{
    const float* x    = (const float*)d_in[0];
    const float* qkvw = (const float*)d_in[1];
    const float* qb   = (const float*)d_in[2];
    const float* vb   = (const float*)d_in[3];
    const float* lqa  = (const float*)d_in[4];
    const float* lqb  = (const float*)d_in[5];
    const float* lka  = (const float*)d_in[6];
    const float* lkb  = (const float*)d_in[7];
    const float* lva  = (const float*)d_in[8];
    const float* lvb  = (const float*)d_in[9];
    const float* rtab = (const float*)d_in[10];
    const float* rcos = (const float*)d_in[11];
    const float* rsin = (const float*)d_in[12];
    const float* pw   = (const float*)d_in[13];
    const float* pb   = (const float*)d_in[14];
    const int* ridx   = (const int*)d_in[15];

    const int M = 64 * 197;                        // 12608
    const size_t XSZ = (size_t)M * 768;            // 9,682,944
    const size_t QSZ = (size_t)64 * 12 * 197 * 64; // 9,682,944

    char* ws = (char*)d_ws;
    unsigned short* xb   = (unsigned short*)ws;                    // XSZ
    unsigned short* pwb  = xb + XSZ;                               // 768*768
    unsigned short* Weff = pwb + (size_t)768 * 768;                // 2304*768
    unsigned short* qsb  = Weff + (size_t)2304 * 768;
    unsigned short* ksb  = qsb + QSZ;
    unsigned short* vsb  = ksb + QSZ;
    float* rpb           = (float*)(vsb + QSZ);                    // 12*197*224 f32
    unsigned short* aout = (unsigned short*)(rpb + (size_t)12 * 197 * 224); // XSZ

    prep_kernel<<<2048, 256, 0, stream>>>(x, xb, pw, pwb, qkvw,
                                          lqa, lqb, lka, lkb, lva, lvb, Weff,
                                          rtab, ridx, rpb);
    gemm_bt<1><<<99 * 18, 512, 0, stream>>>(xb, Weff, M, 2304, 18,
                                            qb, vb, rcos, rsin, qsb, ksb, vsb,
                                            nullptr, nullptr);
    attn_kernel<<<dim3(4, 12, 64), 256, 0, stream>>>(qsb, ksb, vsb, rpb, aout);
    gemm_bt<2><<<99 * 6, 512, 0, stream>>>(aout, pwb, M, 768, 6,
                                           nullptr, nullptr, nullptr, nullptr,
                                           nullptr, nullptr, nullptr,
                                           pb, (float*)d_out);
}